// Round 7
// baseline (611.545 us; speedup 1.0000x reference)
//
#include <hip/hip_runtime.h>
#include <stdint.h>
#include <math.h>

#define SEQ   2048
#define DIM   4096
#define NHEAD 32
#define NKV   8
#define HD    128
#define KVDIM (NKV*HD)   // 1024

typedef __bf16 bf16x8 __attribute__((ext_vector_type(8)));
typedef float  f32x4  __attribute__((ext_vector_type(4)));

__device__ __forceinline__ uint16_t f2bf(float f) {
  uint32_t u = __float_as_uint(f);
  uint32_t r = (u + 0x7FFFu + ((u >> 16) & 1u)) >> 16;
  return (uint16_t)r;
}
__device__ __forceinline__ bf16x8 ld_frag(const uint16_t* p) {
  return *(const bf16x8*)p;
}
__device__ __forceinline__ void async_cp16(const void* g, void* lds) {
  __builtin_amdgcn_global_load_lds(
      (const __attribute__((address_space(1))) void*)g,
      (__attribute__((address_space(3))) void*)lds, 16, 0, 0);
}
__device__ __forceinline__ uint32_t lds_u32(const void* p) {
  return (uint32_t)(uintptr_t)(const __attribute__((address_space(3))) void*)p;
}
__device__ __forceinline__ bf16x8 ds_read_b128a(uint32_t addr) {
  f32x4 r;
  asm volatile("ds_read_b128 %0, %1" : "=v"(r) : "v"(addr));
  return __builtin_bit_cast(bf16x8, r);
}

// ---------------- fused fp32 -> bf16 conversion: x, wq, wk, wv ----------------
__global__ __launch_bounds__(256) void k_conv_all(
    const float* __restrict__ x, const float* __restrict__ wq,
    const float* __restrict__ wk, const float* __restrict__ wv,
    uint16_t* __restrict__ xb, uint16_t* __restrict__ wqkvb) {
  size_t i = (size_t)blockIdx.x * 256 + threadIdx.x;   // float4 index, 8M total
  const float* s; uint16_t* d; size_t off;
  if (i < 2097152)      { s = x;  d = xb;                 off = i; }
  else if (i < 6291456) { s = wq; d = wqkvb;              off = i - 2097152; }
  else if (i < 7340032) { s = wk; d = wqkvb + 16777216u;  off = i - 6291456; }
  else                  { s = wv; d = wqkvb + 20971520u;  off = i - 7340032; }
  const float4 v = ((const float4*)s)[off];
  ushort4 o;
  o.x = f2bf(v.x); o.y = f2bf(v.y); o.z = f2bf(v.z); o.w = f2bf(v.w);
  ((ushort4*)d)[off] = o;
}

__global__ __launch_bounds__(256) void k_conv(const float* __restrict__ s,
                                              uint16_t* __restrict__ d, int n4) {
  int i = blockIdx.x * 256 + threadIdx.x;
  if (i >= n4) return;
  const float4 v = ((const float4*)s)[i];
  ushort4 o;
  o.x = f2bf(v.x); o.y = f2bf(v.y); o.z = f2bf(v.z); o.w = f2bf(v.w);
  ((ushort4*)d)[i] = o;
}

// ======================================================================
// 256x256 NT GEMM core, BK=32, 8 waves (2Mx4N, wave tile 128x64).
// Cross-tile register double-buffer pipeline, ONE barrier per K-tile:
//   body T: stage(T+3) [4 cp16] ; issue 12 ds_read for tile T+1 (setNext)
//           lgkmcnt(12)  <- waits only setCur (prev body's reads)
//           sched_barrier ; setprio(1) ; 32 MFMA on setCur ; setprio(0)
//           vmcnt(4)     <- retires stage(T+2); stage(T+3) stays in flight
//           s_barrier
// ds_reads for T+1 fly UNDER the MFMAs of T (LDS pipe || matrix pipe).
// LDS: ring-4 x (256x32 A + 256x32 B) bf16 = 128 KiB. 3-ahead staging.
// Swizzle: 16B chunk slot c of row r holds global chunk c ^ ((r>>1)&3)
// (pre-swizzled global src for cp16; matching XOR on ds_read) -> 2-way
// bank aliasing only (free). Ring safety: reads of buf[X] retire at
// body X's lgkm before buf[X] restage (body X+1, after barrier);
// buf[T+1] landed before body T reads it (end-of-T-1 vmcnt(4)+barrier,
// per-wave slices block-wide via the barrier). Tail: vmcnt(0) when no
// stage issued. Unroll-by-2 for static set swap (no dyn reg indexing).
// ======================================================================

#define STG32(Tn) do {                                                          \
    const int _rg = ((Tn) & 3) * 8192;                                          \
    async_cp16(gA + (size_t)crow * DIM + (size_t)(Tn) * 32 + cs * 8,            \
               sA + _rg + tid * 8);                                             \
    async_cp16(gA + (size_t)(crow + 128) * DIM + (size_t)(Tn) * 32 + cs * 8,    \
               sA + _rg + 4096 + tid * 8);                                      \
    async_cp16(gB + (size_t)crow * DIM + (size_t)(Tn) * 32 + cs * 8,            \
               sB + _rg + tid * 8);                                             \
    async_cp16(gB + (size_t)(crow + 128) * DIM + (size_t)(Tn) * 32 + cs * 8,    \
               sB + _rg + 4096 + tid * 8);                                      \
  } while (0)

#define READ12(AF, BF, ringoff) do {                                            \
    _Pragma("unroll")                                                           \
    for (int _t = 0; _t < 8; _t++) AF[_t] = ds_read_b128a(offA[_t] + (ringoff));\
    _Pragma("unroll")                                                           \
    for (int _u = 0; _u < 4; _u++) BF[_u] = ds_read_b128a(offB[_u] + (ringoff));\
  } while (0)

#define MFMA32(AF, BF)                                                          \
    _Pragma("unroll")                                                           \
    for (int _t = 0; _t < 8; _t++)                                              \
      _Pragma("unroll")                                                         \
      for (int _u = 0; _u < 4; _u++)                                            \
        acc[_t][_u] = __builtin_amdgcn_mfma_f32_16x16x32_bf16(AF[_t], BF[_u],   \
                                                              acc[_t][_u], 0, 0, 0);

#define BODY(CA, CB, NA, NB, T) do {                                            \
    if ((T) + 3 < 128) STG32((T) + 3);                                          \
    if ((T) + 1 < 128) {                                                        \
      const uint32_t _ro = (uint32_t)((((T) + 1) & 3) << 14);                   \
      READ12(NA, NB, _ro);                                                      \
      asm volatile("s_waitcnt lgkmcnt(12)" ::: "memory");                       \
    } else {                                                                    \
      asm volatile("s_waitcnt lgkmcnt(0)" ::: "memory");                        \
    }                                                                           \
    __builtin_amdgcn_sched_barrier(0);                                          \
    __builtin_amdgcn_s_setprio(1);                                              \
    MFMA32(CA, CB);                                                             \
    __builtin_amdgcn_s_setprio(0);                                              \
    if ((T) + 3 < 128) { asm volatile("s_waitcnt vmcnt(4)" ::: "memory"); }     \
    else               { asm volatile("s_waitcnt vmcnt(0)" ::: "memory"); }     \
    if ((T) < 127) __builtin_amdgcn_s_barrier();                                \
  } while (0)

#define G256_PROLOGUE(Aptr, Bptr)                                               \
  __shared__ __align__(16) uint16_t sA[4 * 8192];                               \
  __shared__ __align__(16) uint16_t sB[4 * 8192];                               \
  const int tid  = threadIdx.x;                                                 \
  const int lane = tid & 63;                                                    \
  const int wv   = tid >> 6;                                                    \
  const int quad = lane >> 4;                                                   \
  const int l16  = lane & 15;                                                   \
  const int wm   = (wv >> 2) << 7;   /* 0 or 128 */                             \
  const int wn   = (wv & 3) << 6;    /* 0,64,128,192 */                         \
  const uint16_t* gA = Aptr + (size_t)m0 * DIM;                                 \
  const uint16_t* gB = Bptr + (size_t)n0 * DIM;                                 \
  const int crow = tid >> 2;                                                    \
  const int cs   = (tid & 3) ^ ((crow >> 1) & 3);                               \
  const uint32_t sAb = lds_u32(sA);                                             \
  const uint32_t sBb = lds_u32(sB);                                             \
  uint32_t offA[8], offB[4];                                                    \
  _Pragma("unroll")                                                             \
  for (int t = 0; t < 8; t++) {                                                 \
    int r_ = wm + t * 16 + l16;                                                 \
    offA[t] = sAb + (uint32_t)(r_ * 64 + (quad ^ ((r_ >> 1) & 3)) * 16);        \
  }                                                                             \
  _Pragma("unroll")                                                             \
  for (int u = 0; u < 4; u++) {                                                 \
    int r_ = wn + u * 16 + l16;                                                 \
    offB[u] = sBb + (uint32_t)(r_ * 64 + (quad ^ ((r_ >> 1) & 3)) * 16);        \
  }                                                                             \
  f32x4 acc[8][4] = {};                                                         \
  bf16x8 afC[8], bfC[4], afN[8], bfN[4];                                        \
  STG32(0); STG32(1); STG32(2);                                                 \
  asm volatile("s_waitcnt vmcnt(4)" ::: "memory");  /* tiles 0,1 landed */      \
  __builtin_amdgcn_s_barrier();                                                 \
  READ12(afC, bfC, 0u);                                                         \
  for (int T = 0; T < 128; T += 2) {                                            \
    BODY(afC, bfC, afN, bfN, T);                                                \
    BODY(afN, bfN, afC, bfC, T + 1);                                            \
  }

// ---- merged QKV GEMM with fused RoPE epilogue ----
__global__ __launch_bounds__(512, 2) void k_gemm_qkv(
    const uint16_t* __restrict__ xb, const uint16_t* __restrict__ wqkvb,
    uint16_t* __restrict__ Qb, uint16_t* __restrict__ Kb, uint16_t* __restrict__ Vb)
{
  const int bx = blockIdx.x;          // 0..23
  const int m0 = blockIdx.y * 256;
  const int n0 = bx * 256;            // weight row base (0..6143)
  G256_PROLOGUE(xb, wqkvb)

  const int region = (bx < 16) ? 0 : (bx < 20 ? 1 : 2);  // Q / K / V
  uint16_t* outp; int ldC, cbase;
  if (region == 0)      { outp = Qb; ldC = DIM;   cbase = n0; }
  else if (region == 1) { outp = Kb; ldC = KVDIM; cbase = n0 - 4096; }
  else                  { outp = Vb; ldC = KVDIM; cbase = n0 - 5120; }

  #pragma unroll
  for (int t = 0; t < 8; t++)
    #pragma unroll
    for (int u = 0; u < 4; u++) {
      const int col = cbase + wn + u * 16 + l16;
      const int d = col & 127;
      const float freq = expf(-0.20503693f * (float)(d >> 1));
      const float sgn = (d & 1) ? 1.0f : -1.0f;
      #pragma unroll
      for (int r = 0; r < 4; r++) {
        const int row = m0 + wm + t * 16 + quad * 4 + r;
        float v = acc[t][u][r];
        if (region < 2) {   // RoPE: pair lives in adjacent l16 lane
          float p = __shfl_xor(v, 1, 64);
          float ang = (float)row * freq;
          float sn, cc2;
          sincosf(ang, &sn, &cc2);
          v = v * cc2 + p * sn * sgn;
        }
        outp[(size_t)row * ldC + col] = f2bf(v);
      }
    }
}

// ---- O-projection GEMM (fp32 out) ----
__global__ __launch_bounds__(512, 2) void k_gemm_o(
    const uint16_t* __restrict__ ab, const uint16_t* __restrict__ wob,
    float* __restrict__ out)
{
  const int m0 = blockIdx.y * 256;
  const int n0 = blockIdx.x * 256;
  G256_PROLOGUE(ab, wob)
  #pragma unroll
  for (int t = 0; t < 8; t++)
    #pragma unroll
    for (int u = 0; u < 4; u++)
      #pragma unroll
      for (int r = 0; r < 4; r++) {
        int row = m0 + wm + t * 16 + quad * 4 + r;
        int col = n0 + wn + u * 16 + l16;
        out[(size_t)row * DIM + col] = acc[t][u][r];
      }
}

// ---------------- V transpose: V[s][kvh*128+d] -> VT[kvh][d][s] ----------------
__global__ __launch_bounds__(256) void k_vtrans(const uint16_t* __restrict__ Vb,
                                                uint16_t* __restrict__ VT) {
  __shared__ uint16_t t[64][72];
  const int s0 = blockIdx.x * 64;
  const int c0 = blockIdx.y * 64;
  const int tid = threadIdx.x;
  #pragma unroll
  for (int i = 0; i < 2; i++) {
    int idx = i * 256 + tid;
    int r = idx >> 3, ch = idx & 7;
    uint4 dv = *(const uint4*)(Vb + (size_t)(s0 + r) * KVDIM + c0 + ch * 8);
    *(uint4*)(&t[r][ch * 8]) = dv;
  }
  __syncthreads();
  const int kvh = c0 >> 7;
  const int dbase = c0 & 127;
  #pragma unroll
  for (int i = 0; i < 2; i++) {
    int idx = i * 256 + tid;
    int d = idx >> 3, sc = idx & 7;
    uint16_t tmp[8];
    #pragma unroll
    for (int j2 = 0; j2 < 8; j2++) tmp[j2] = t[sc * 8 + j2][d];
    *(uint4*)(VT + (size_t)kvh * HD * SEQ + (size_t)(dbase + d) * SEQ + s0 + sc * 8) = *(const uint4*)tmp;
  }
}

// ---------------- Split-KV flash attention, fixed-shift softmax ----------------
#define BKV 64
#define NPAIR 40
__device__ __constant__ uint8_t c_pair[NPAIR] = {
  12,16,20,24,28,29,32,33,36,37,40,41,44,45,46,48,49,50,52,53,54,56,57,58,60,61,62,63, // 8-iter
  8,25,42,59,   // 6-iter
  4,21,38,55,   // 4-iter
  0,17,34,51    // 2-iter
};
__device__ __constant__ uint8_t c_base[16] = {0,1,2,3,4,6,8,10,12,15,18,21,24,28,32,36};

__global__ __launch_bounds__(256) void k_flash_split(
    const uint16_t* __restrict__ Qb, const uint16_t* __restrict__ Kb,
    const uint16_t* __restrict__ VT, uint16_t* __restrict__ Opart,
    float* __restrict__ ml)
{
  const int pair = c_pair[blockIdx.x];
  const int qt   = pair >> 2;
  const int seg  = pair & 3;
  const int h    = blockIdx.y;
  const int kvh  = h >> 2;
  const int slot = h * NPAIR + c_base[qt] + seg;
  const int tid  = threadIdx.x;
  const int lane = tid & 63;
  const int wv   = tid >> 6;
  const int quad = lane >> 4;
  const int l16  = lane & 15;
  const int q0   = qt * 128;

  __shared__ __align__(16) uint16_t sK[BKV * 128];
  __shared__ __align__(16) uint16_t sVT[HD * BKV];
  __shared__ __align__(16) uint16_t sP[4 * 32 * 72];

  const uint16_t* Kbase  = Kb + kvh * HD;
  const uint16_t* VTbase = VT + (size_t)kvh * HD * SEQ;

  bf16x8 qf[2][4];
  #pragma unroll
  for (int mt = 0; mt < 2; mt++)
    #pragma unroll
    for (int ks = 0; ks < 4; ks++)
      qf[mt][ks] = ld_frag(Qb + (size_t)(q0 + wv * 32 + mt * 16 + l16) * DIM + h * HD + ks * 32 + quad * 8);

  __align__(16) uint16_t ones_bits[8];
  #pragma unroll
  for (int j = 0; j < 8; j++) ones_bits[j] = (l16 == 0) ? 0x3F80 : 0;
  const bf16x8 onesf = *(const bf16x8*)ones_bits;

  f32x4 Oacc[2][8] = {};
  f32x4 Lacc[2] = {};

  const float scale = 0.08838834764831845f;  // 1/sqrt(128)
  const float MFIX = 12.0f;
  const int j0 = seg * 8;
  const int j1 = min(j0 + 8, 2 * (qt + 1));

  for (int j = j0; j < j1; j++) {
    const int t0 = j * BKV;
    #pragma unroll
    for (int i = 0; i < 4; i++) {
      int pos = i * 256 + tid;
      int row = pos >> 4, g = (pos & 15) ^ (row & 7);
      async_cp16(Kbase + (size_t)(t0 + row) * KVDIM + g * 8, sK + pos * 8);
      int vrow = pos >> 3, vg = (pos & 7) ^ (vrow & 7);
      async_cp16(VTbase + (size_t)vrow * SEQ + t0 + vg * 8, sVT + pos * 8);
    }
    __syncthreads();

    bool active = (t0 <= q0 + wv * 32 + 31);  // wave-uniform
    if (active) {
      f32x4 Sacc[2][4] = {};
      #pragma unroll
      for (int ks = 0; ks < 4; ks++) {
        bf16x8 kf[4];
        #pragma unroll
        for (int nt = 0; nt < 4; nt++)
          kf[nt] = ld_frag(sK + (nt * 16 + l16) * 128 + (((ks * 4 + quad) ^ (l16 & 7)) * 8));
        #pragma unroll
        for (int mt = 0; mt < 2; mt++)
          #pragma unroll
          for (int nt = 0; nt < 4; nt++)
            Sacc[mt][nt] = __builtin_amdgcn_mfma_f32_16x16x32_bf16(qf[mt][ks], kf[nt], Sacc[mt][nt], 0, 0, 0);
      }
      const bool diag = (t0 + BKV - 1) > (q0 + wv * 32);
      #pragma unroll
      for (int mt = 0; mt < 2; mt++)
        #pragma unroll
        for (int nt = 0; nt < 4; nt++)
          #pragma unroll
          for (int r = 0; r < 4; r++) {
            float sv = Sacc[mt][nt][r] * scale - MFIX;
            bool msk = false;
            if (diag) {
              int qg = q0 + wv * 32 + mt * 16 + quad * 4 + r;
              int tg = t0 + nt * 16 + l16;
              msk = tg > qg;
            }
            float pv = msk ? 0.0f : __expf(sv);
            sP[(wv * 32 + mt * 16 + quad * 4 + r) * 72 + nt * 16 + l16] = f2bf(pv);
          }
      #pragma unroll
      for (int ks = 0; ks < 2; ks++) {
        bf16x8 pf[2], vf[8];
        #pragma unroll
        for (int mt = 0; mt < 2; mt++)
          pf[mt] = ld_frag(sP + (wv * 32 + mt * 16 + l16) * 72 + ks * 32 + quad * 8);
        #pragma unroll
        for (int dt = 0; dt < 8; dt++)
          vf[dt] = ld_frag(sVT + (dt * 16 + l16) * 64 + (((ks * 4 + quad) ^ (l16 & 7)) * 8));
        #pragma unroll
        for (int mt = 0; mt < 2; mt++) {
          Lacc[mt] = __builtin_amdgcn_mfma_f32_16x16x32_bf16(pf[mt], onesf, Lacc[mt], 0, 0, 0);
          #pragma unroll
          for (int dt = 0; dt < 8; dt++)
            Oacc[mt][dt] = __builtin_amdgcn_mfma_f32_16x16x32_bf16(pf[mt], vf[dt], Oacc[mt][dt], 0, 0, 0);
        }
      }
    }
    __syncthreads();
  }

  uint16_t* Op = Opart + (size_t)slot * (128 * 128);
  #pragma unroll
  for (int mt = 0; mt < 2; mt++)
    #pragma unroll
    for (int r = 0; r < 4; r++) {
      int row = wv * 32 + mt * 16 + quad * 4 + r;
      #pragma unroll
      for (int dt = 0; dt < 8; dt++)
        Op[row * 128 + dt * 16 + l16] = f2bf(Oacc[mt][dt][r]);
      if (l16 == 0)
        ml[(size_t)slot * 128 + row] = Lacc[mt][r];
    }
}

// ---------------- combine partials -> attn output (bf16) ----------------
__global__ __launch_bounds__(256) void k_combine(
    const uint16_t* __restrict__ Opart, const float* __restrict__ ml,
    uint16_t* __restrict__ attnb)
{
  const int qt = blockIdx.x;
  const int h  = blockIdx.y;
  const int nseg = (qt >> 2) + 1;
  const int slot0 = h * NPAIR + c_base[qt];
  const int tid = threadIdx.x;
  const int row = tid >> 1;
  const int dh  = (tid & 1) * 64;

  float L = 0.0f;
  #pragma unroll
  for (int i = 0; i < 4; i++)
    if (i < nseg) L += ml[(size_t)(slot0 + i) * 128 + row];
  const float invL = 1.0f / L;

  uint16_t* dst = attnb + (size_t)(qt * 128 + row) * DIM + h * HD + dh;
  #pragma unroll
  for (int c = 0; c < 8; c++) {
    int d = dh + c * 8;
    float acc[8] = {};
    #pragma unroll
    for (int i = 0; i < 4; i++) {
      if (i < nseg) {
        bf16x8 v = ld_frag(Opart + (size_t)(slot0 + i) * (128 * 128) + row * 128 + d);
        #pragma unroll
        for (int j = 0; j < 8; j++) acc[j] += (float)v[j];
      }
    }
    uint16_t outv[8];
    #pragma unroll
    for (int j = 0; j < 8; j++) outv[j] = f2bf(acc[j] * invL);
    *(uint4*)(dst + c * 8) = *(const uint4*)outv;
  }
}

// ---------------- launch ----------------
extern "C" void kernel_launch(void* const* d_in, const int* in_sizes, int n_in,
                              void* d_out, int out_size, void* d_ws, size_t ws_size,
                              hipStream_t stream) {
  const float* x  = (const float*)d_in[0];
  const float* wq = (const float*)d_in[1];
  const float* wk = (const float*)d_in[2];
  const float* wv = (const float*)d_in[3];
  const float* wo = (const float*)d_in[4];
  float* out = (float*)d_out;

  uint8_t* ws = (uint8_t*)d_ws;
  uint16_t* xb     = (uint16_t*)(ws + 0);
  uint16_t* wqkvb  = (uint16_t*)(ws + 16777216ull);
  uint16_t* Qb     = (uint16_t*)(ws + 67108864ull);
  uint16_t* Kb     = (uint16_t*)(ws + 83886080ull);
  uint16_t* Vb     = (uint16_t*)(ws + 88080384ull);
  uint16_t* VT     = (uint16_t*)(ws + 16777216ull);
  uint16_t* Opart  = (uint16_t*)(ws + 20971520ull);
  float*    mlbuf  = (float*)   (ws + 62914560ull);
  uint16_t* wob    = (uint16_t*)(ws + 16777216ull);
  uint16_t* attnb  = xb;

  k_conv_all<<<32768, 256, 0, stream>>>(x, wq, wk, wv, xb, wqkvb);
  k_gemm_qkv<<<dim3(24, 8), 512, 0, stream>>>(xb, wqkvb, Qb, Kb, Vb);
  k_vtrans<<<dim3(32, 16), 256, 0, stream>>>(Vb, VT);
  k_flash_split<<<dim3(NPAIR, 32), 256, 0, stream>>>(Qb, Kb, VT, Opart, mlbuf);
  k_combine<<<dim3(16, 32), 256, 0, stream>>>(Opart, mlbuf, attnb);
  k_conv<<<16384, 256, 0, stream>>>(wo, wob, 4194304);
  k_gemm_o<<<dim3(16, 8), 512, 0, stream>>>(attnb, wob, out);
}

// Round 8
// 574.787 us; speedup vs baseline: 1.0640x; 1.0640x over previous
//
#include <hip/hip_runtime.h>
#include <stdint.h>
#include <math.h>

#define SEQ   2048
#define DIM   4096
#define NHEAD 32
#define NKV   8
#define HD    128
#define KVDIM (NKV*HD)   // 1024

typedef __bf16 bf16x8 __attribute__((ext_vector_type(8)));
typedef float  f32x4  __attribute__((ext_vector_type(4)));

__device__ __forceinline__ uint16_t f2bf(float f) {
  uint32_t u = __float_as_uint(f);
  uint32_t r = (u + 0x7FFFu + ((u >> 16) & 1u)) >> 16;
  return (uint16_t)r;
}
__device__ __forceinline__ bf16x8 ld_frag(const uint16_t* p) {
  return *(const bf16x8*)p;
}
__device__ __forceinline__ void async_cp16(const void* g, void* lds) {
  __builtin_amdgcn_global_load_lds(
      (const __attribute__((address_space(1))) void*)g,
      (__attribute__((address_space(3))) void*)lds, 16, 0, 0);
}
__device__ __forceinline__ uint32_t lds_u32(const void* p) {
  return (uint32_t)(uintptr_t)(const __attribute__((address_space(3))) void*)p;
}
__device__ __forceinline__ bf16x8 ds_read_b128a(uint32_t addr) {
  f32x4 r;
  asm volatile("ds_read_b128 %0, %1" : "=v"(r) : "v"(addr));
  return __builtin_bit_cast(bf16x8, r);
}

// ---------------- fused fp32 -> bf16 conversion: x, wq, wk, wv ----------------
__global__ __launch_bounds__(256) void k_conv_all(
    const float* __restrict__ x, const float* __restrict__ wq,
    const float* __restrict__ wk, const float* __restrict__ wv,
    uint16_t* __restrict__ xb, uint16_t* __restrict__ wqkvb) {
  size_t i = (size_t)blockIdx.x * 256 + threadIdx.x;   // float4 index, 8M total
  const float* s; uint16_t* d; size_t off;
  if (i < 2097152)      { s = x;  d = xb;                 off = i; }
  else if (i < 6291456) { s = wq; d = wqkvb;              off = i - 2097152; }
  else if (i < 7340032) { s = wk; d = wqkvb + 16777216u;  off = i - 6291456; }
  else                  { s = wv; d = wqkvb + 20971520u;  off = i - 7340032; }
  const float4 v = ((const float4*)s)[off];
  ushort4 o;
  o.x = f2bf(v.x); o.y = f2bf(v.y); o.z = f2bf(v.z); o.w = f2bf(v.w);
  ((ushort4*)d)[off] = o;
}

__global__ __launch_bounds__(256) void k_conv(const float* __restrict__ s,
                                              uint16_t* __restrict__ d, int n4) {
  int i = blockIdx.x * 256 + threadIdx.x;
  if (i >= n4) return;
  const float4 v = ((const float4*)s)[i];
  ushort4 o;
  o.x = f2bf(v.x); o.y = f2bf(v.y); o.z = f2bf(v.z); o.w = f2bf(v.w);
  ((ushort4*)d)[i] = o;
}

// ======================================================================
// 256x256 NT GEMM core for QKV (unchanged from R7): BK=32, 8 waves,
// cross-tile register double-buffer, one barrier per K-tile, ring-4 LDS.
// ======================================================================

#define STG32(Tn) do {                                                          \
    const int _rg = ((Tn) & 3) * 8192;                                          \
    async_cp16(gA + (size_t)crow * DIM + (size_t)(Tn) * 32 + cs * 8,            \
               sA + _rg + tid * 8);                                             \
    async_cp16(gA + (size_t)(crow + 128) * DIM + (size_t)(Tn) * 32 + cs * 8,    \
               sA + _rg + 4096 + tid * 8);                                      \
    async_cp16(gB + (size_t)crow * DIM + (size_t)(Tn) * 32 + cs * 8,            \
               sB + _rg + tid * 8);                                             \
    async_cp16(gB + (size_t)(crow + 128) * DIM + (size_t)(Tn) * 32 + cs * 8,    \
               sB + _rg + 4096 + tid * 8);                                      \
  } while (0)

#define READ12(AF, BF, ringoff) do {                                            \
    _Pragma("unroll")                                                           \
    for (int _t = 0; _t < 8; _t++) AF[_t] = ds_read_b128a(offA[_t] + (ringoff));\
    _Pragma("unroll")                                                           \
    for (int _u = 0; _u < 4; _u++) BF[_u] = ds_read_b128a(offB[_u] + (ringoff));\
  } while (0)

#define MFMA32(AF, BF)                                                          \
    _Pragma("unroll")                                                           \
    for (int _t = 0; _t < 8; _t++)                                              \
      _Pragma("unroll")                                                         \
      for (int _u = 0; _u < 4; _u++)                                            \
        acc[_t][_u] = __builtin_amdgcn_mfma_f32_16x16x32_bf16(AF[_t], BF[_u],   \
                                                              acc[_t][_u], 0, 0, 0);

#define BODY(CA, CB, NA, NB, T) do {                                            \
    if ((T) + 3 < 128) STG32((T) + 3);                                          \
    if ((T) + 1 < 128) {                                                        \
      const uint32_t _ro = (uint32_t)((((T) + 1) & 3) << 14);                   \
      READ12(NA, NB, _ro);                                                      \
      asm volatile("s_waitcnt lgkmcnt(12)" ::: "memory");                       \
    } else {                                                                    \
      asm volatile("s_waitcnt lgkmcnt(0)" ::: "memory");                        \
    }                                                                           \
    __builtin_amdgcn_sched_barrier(0);                                          \
    __builtin_amdgcn_s_setprio(1);                                              \
    MFMA32(CA, CB);                                                             \
    __builtin_amdgcn_s_setprio(0);                                              \
    if ((T) + 3 < 128) { asm volatile("s_waitcnt vmcnt(4)" ::: "memory"); }     \
    else               { asm volatile("s_waitcnt vmcnt(0)" ::: "memory"); }     \
    if ((T) < 127) __builtin_amdgcn_s_barrier();                                \
  } while (0)

#define G256_PROLOGUE(Aptr, Bptr)                                               \
  __shared__ __align__(16) uint16_t sA[4 * 8192];                               \
  __shared__ __align__(16) uint16_t sB[4 * 8192];                               \
  const int tid  = threadIdx.x;                                                 \
  const int lane = tid & 63;                                                    \
  const int wv   = tid >> 6;                                                    \
  const int quad = lane >> 4;                                                   \
  const int l16  = lane & 15;                                                   \
  const int wm   = (wv >> 2) << 7;   /* 0 or 128 */                             \
  const int wn   = (wv & 3) << 6;    /* 0,64,128,192 */                         \
  const uint16_t* gA = Aptr + (size_t)m0 * DIM;                                 \
  const uint16_t* gB = Bptr + (size_t)n0 * DIM;                                 \
  const int crow = tid >> 2;                                                    \
  const int cs   = (tid & 3) ^ ((crow >> 1) & 3);                               \
  const uint32_t sAb = lds_u32(sA);                                             \
  const uint32_t sBb = lds_u32(sB);                                             \
  uint32_t offA[8], offB[4];                                                    \
  _Pragma("unroll")                                                             \
  for (int t = 0; t < 8; t++) {                                                 \
    int r_ = wm + t * 16 + l16;                                                 \
    offA[t] = sAb + (uint32_t)(r_ * 64 + (quad ^ ((r_ >> 1) & 3)) * 16);        \
  }                                                                             \
  _Pragma("unroll")                                                             \
  for (int u = 0; u < 4; u++) {                                                 \
    int r_ = wn + u * 16 + l16;                                                 \
    offB[u] = sBb + (uint32_t)(r_ * 64 + (quad ^ ((r_ >> 1) & 3)) * 16);        \
  }                                                                             \
  f32x4 acc[8][4] = {};                                                         \
  bf16x8 afC[8], bfC[4], afN[8], bfN[4];                                        \
  STG32(0); STG32(1); STG32(2);                                                 \
  asm volatile("s_waitcnt vmcnt(4)" ::: "memory");  /* tiles 0,1 landed */      \
  __builtin_amdgcn_s_barrier();                                                 \
  READ12(afC, bfC, 0u);                                                         \
  for (int T = 0; T < 128; T += 2) {                                            \
    BODY(afC, bfC, afN, bfN, T);                                                \
    BODY(afN, bfN, afC, bfC, T + 1);                                            \
  }

// ---- merged QKV GEMM with fused RoPE epilogue ----
__global__ __launch_bounds__(512, 2) void k_gemm_qkv(
    const uint16_t* __restrict__ xb, const uint16_t* __restrict__ wqkvb,
    uint16_t* __restrict__ Qb, uint16_t* __restrict__ Kb, uint16_t* __restrict__ Vb)
{
  const int bx = blockIdx.x;          // 0..23
  const int m0 = blockIdx.y * 256;
  const int n0 = bx * 256;            // weight row base (0..6143)
  G256_PROLOGUE(xb, wqkvb)

  const int region = (bx < 16) ? 0 : (bx < 20 ? 1 : 2);  // Q / K / V
  uint16_t* outp; int ldC, cbase;
  if (region == 0)      { outp = Qb; ldC = DIM;   cbase = n0; }
  else if (region == 1) { outp = Kb; ldC = KVDIM; cbase = n0 - 4096; }
  else                  { outp = Vb; ldC = KVDIM; cbase = n0 - 5120; }

  #pragma unroll
  for (int t = 0; t < 8; t++)
    #pragma unroll
    for (int u = 0; u < 4; u++) {
      const int col = cbase + wn + u * 16 + l16;
      const int d = col & 127;
      const float freq = expf(-0.20503693f * (float)(d >> 1));
      const float sgn = (d & 1) ? 1.0f : -1.0f;
      #pragma unroll
      for (int r = 0; r < 4; r++) {
        const int row = m0 + wm + t * 16 + quad * 4 + r;
        float v = acc[t][u][r];
        if (region < 2) {   // RoPE: pair lives in adjacent l16 lane
          float p = __shfl_xor(v, 1, 64);
          float ang = (float)row * freq;
          float sn, cc2;
          sincosf(ang, &sn, &cc2);
          v = v * cc2 + p * sn * sgn;
        }
        outp[(size_t)row * ldC + col] = f2bf(v);
      }
    }
}

// ======================================================================
// 128x256 NT GEMM for O-projection: grid 16x16 = 256 blocks (full fill).
// Same pipeline: BK=32, ring-4 LDS (A 32KB + B 64KB = 96 KiB), 8 waves
// (wave tile 64x64), 3 cp16/thread/tile, reads 4A+4B, 16 MFMA/wave,
// counted vmcnt(3)/lgkmcnt(8), one barrier per K-tile.
// ======================================================================

#define O_STG(Tn) do {                                                          \
    const int _ra = ((Tn) & 3) * 4096;                                          \
    const int _rb = ((Tn) & 3) * 8192;                                          \
    async_cp16(gA + (size_t)crow * DIM + (size_t)(Tn) * 32 + cs * 8,            \
               sA + _ra + tid * 8);                                             \
    async_cp16(gB + (size_t)crow * DIM + (size_t)(Tn) * 32 + cs * 8,            \
               sB + _rb + tid * 8);                                             \
    async_cp16(gB + (size_t)(crow + 128) * DIM + (size_t)(Tn) * 32 + cs * 8,    \
               sB + _rb + 4096 + tid * 8);                                      \
  } while (0)

#define O_BODY(CA, CB, NA, NB, T) do {                                          \
    if ((T) + 3 < 128) O_STG((T) + 3);                                          \
    if ((T) + 1 < 128) {                                                        \
      const uint32_t _ra = (uint32_t)((((T) + 1) & 3) << 13);                   \
      const uint32_t _rb = (uint32_t)((((T) + 1) & 3) << 14);                   \
      _Pragma("unroll")                                                         \
      for (int _t = 0; _t < 4; _t++) NA[_t] = ds_read_b128a(offA[_t] + _ra);    \
      _Pragma("unroll")                                                         \
      for (int _u = 0; _u < 4; _u++) NB[_u] = ds_read_b128a(offB[_u] + _rb);    \
      asm volatile("s_waitcnt lgkmcnt(8)" ::: "memory");                        \
    } else {                                                                    \
      asm volatile("s_waitcnt lgkmcnt(0)" ::: "memory");                        \
    }                                                                           \
    __builtin_amdgcn_sched_barrier(0);                                          \
    __builtin_amdgcn_s_setprio(1);                                              \
    _Pragma("unroll")                                                           \
    for (int _t = 0; _t < 4; _t++)                                              \
      _Pragma("unroll")                                                         \
      for (int _u = 0; _u < 4; _u++)                                            \
        acc[_t][_u] = __builtin_amdgcn_mfma_f32_16x16x32_bf16(CA[_t], CB[_u],   \
                                                              acc[_t][_u], 0, 0, 0); \
    __builtin_amdgcn_s_setprio(0);                                              \
    if ((T) + 3 < 128) { asm volatile("s_waitcnt vmcnt(3)" ::: "memory"); }     \
    else               { asm volatile("s_waitcnt vmcnt(0)" ::: "memory"); }     \
    if ((T) < 127) __builtin_amdgcn_s_barrier();                                \
  } while (0)

__global__ __launch_bounds__(512, 2) void k_gemm_o(
    const uint16_t* __restrict__ ab, const uint16_t* __restrict__ wob,
    float* __restrict__ out)
{
  __shared__ __align__(16) uint16_t sA[4 * 4096];   // 32 KiB
  __shared__ __align__(16) uint16_t sB[4 * 8192];   // 64 KiB
  const int m0 = blockIdx.y * 128;
  const int n0 = blockIdx.x * 256;
  const int tid  = threadIdx.x;
  const int lane = tid & 63;
  const int wv   = tid >> 6;
  const int quad = lane >> 4;
  const int l16  = lane & 15;
  const int wm   = (wv >> 2) << 6;   // 0 or 64
  const int wn   = (wv & 3) << 6;    // 0,64,128,192
  const uint16_t* gA = ab  + (size_t)m0 * DIM;
  const uint16_t* gB = wob + (size_t)n0 * DIM;
  const int crow = tid >> 2;
  const int cs   = (tid & 3) ^ ((crow >> 1) & 3);
  const uint32_t sAb = lds_u32(sA);
  const uint32_t sBb = lds_u32(sB);
  uint32_t offA[4], offB[4];
  #pragma unroll
  for (int t = 0; t < 4; t++) {
    int r_ = wm + t * 16 + l16;
    offA[t] = sAb + (uint32_t)(r_ * 64 + (quad ^ ((r_ >> 1) & 3)) * 16);
  }
  #pragma unroll
  for (int u = 0; u < 4; u++) {
    int r_ = wn + u * 16 + l16;
    offB[u] = sBb + (uint32_t)(r_ * 64 + (quad ^ ((r_ >> 1) & 3)) * 16);
  }
  f32x4 acc[4][4] = {};
  bf16x8 afC[4], bfC[4], afN[4], bfN[4];
  O_STG(0); O_STG(1); O_STG(2);
  asm volatile("s_waitcnt vmcnt(3)" ::: "memory");  // tiles 0,1 landed
  __builtin_amdgcn_s_barrier();
  #pragma unroll
  for (int _t = 0; _t < 4; _t++) afC[_t] = ds_read_b128a(offA[_t]);
  #pragma unroll
  for (int _u = 0; _u < 4; _u++) bfC[_u] = ds_read_b128a(offB[_u]);
  for (int T = 0; T < 128; T += 2) {
    O_BODY(afC, bfC, afN, bfN, T);
    O_BODY(afN, bfN, afC, bfC, T + 1);
  }
  asm volatile("s_waitcnt vmcnt(0)" ::: "memory");
  #pragma unroll
  for (int t = 0; t < 4; t++)
    #pragma unroll
    for (int u = 0; u < 4; u++)
      #pragma unroll
      for (int r = 0; r < 4; r++) {
        int row = m0 + wm + t * 16 + quad * 4 + r;
        int col = n0 + wn + u * 16 + l16;
        out[(size_t)row * DIM + col] = acc[t][u][r];
      }
}

// ---------------- V transpose: V[s][kvh*128+d] -> VT[kvh][d][s] ----------------
__global__ __launch_bounds__(256) void k_vtrans(const uint16_t* __restrict__ Vb,
                                                uint16_t* __restrict__ VT) {
  __shared__ uint16_t t[64][72];
  const int s0 = blockIdx.x * 64;
  const int c0 = blockIdx.y * 64;
  const int tid = threadIdx.x;
  #pragma unroll
  for (int i = 0; i < 2; i++) {
    int idx = i * 256 + tid;
    int r = idx >> 3, ch = idx & 7;
    uint4 dv = *(const uint4*)(Vb + (size_t)(s0 + r) * KVDIM + c0 + ch * 8);
    *(uint4*)(&t[r][ch * 8]) = dv;
  }
  __syncthreads();
  const int kvh = c0 >> 7;
  const int dbase = c0 & 127;
  #pragma unroll
  for (int i = 0; i < 2; i++) {
    int idx = i * 256 + tid;
    int d = idx >> 3, sc = idx & 7;
    uint16_t tmp[8];
    #pragma unroll
    for (int j2 = 0; j2 < 8; j2++) tmp[j2] = t[sc * 8 + j2][d];
    *(uint4*)(VT + (size_t)kvh * HD * SEQ + (size_t)(dbase + d) * SEQ + s0 + sc * 8) = *(const uint4*)tmp;
  }
}

// ---------------- Split-KV flash attention, fixed-shift softmax ----------------
#define BKV 64
#define NPAIR 40
__device__ __constant__ uint8_t c_pair[NPAIR] = {
  12,16,20,24,28,29,32,33,36,37,40,41,44,45,46,48,49,50,52,53,54,56,57,58,60,61,62,63, // 8-iter
  8,25,42,59,   // 6-iter
  4,21,38,55,   // 4-iter
  0,17,34,51    // 2-iter
};
__device__ __constant__ uint8_t c_base[16] = {0,1,2,3,4,6,8,10,12,15,18,21,24,28,32,36};

__global__ __launch_bounds__(256) void k_flash_split(
    const uint16_t* __restrict__ Qb, const uint16_t* __restrict__ Kb,
    const uint16_t* __restrict__ VT, uint16_t* __restrict__ Opart,
    float* __restrict__ ml)
{
  const int pair = c_pair[blockIdx.x];
  const int qt   = pair >> 2;
  const int seg  = pair & 3;
  const int h    = blockIdx.y;
  const int kvh  = h >> 2;
  const int slot = h * NPAIR + c_base[qt] + seg;
  const int tid  = threadIdx.x;
  const int lane = tid & 63;
  const int wv   = tid >> 6;
  const int quad = lane >> 4;
  const int l16  = lane & 15;
  const int q0   = qt * 128;

  __shared__ __align__(16) uint16_t sK[BKV * 128];
  __shared__ __align__(16) uint16_t sVT[HD * BKV];
  __shared__ __align__(16) uint16_t sP[4 * 32 * 72];

  const uint16_t* Kbase  = Kb + kvh * HD;
  const uint16_t* VTbase = VT + (size_t)kvh * HD * SEQ;

  bf16x8 qf[2][4];
  #pragma unroll
  for (int mt = 0; mt < 2; mt++)
    #pragma unroll
    for (int ks = 0; ks < 4; ks++)
      qf[mt][ks] = ld_frag(Qb + (size_t)(q0 + wv * 32 + mt * 16 + l16) * DIM + h * HD + ks * 32 + quad * 8);

  __align__(16) uint16_t ones_bits[8];
  #pragma unroll
  for (int j = 0; j < 8; j++) ones_bits[j] = (l16 == 0) ? 0x3F80 : 0;
  const bf16x8 onesf = *(const bf16x8*)ones_bits;

  f32x4 Oacc[2][8] = {};
  f32x4 Lacc[2] = {};

  const float scale = 0.08838834764831845f;  // 1/sqrt(128)
  const float MFIX = 12.0f;
  const int j0 = seg * 8;
  const int j1 = min(j0 + 8, 2 * (qt + 1));

  for (int j = j0; j < j1; j++) {
    const int t0 = j * BKV;
    #pragma unroll
    for (int i = 0; i < 4; i++) {
      int pos = i * 256 + tid;
      int row = pos >> 4, g = (pos & 15) ^ (row & 7);
      async_cp16(Kbase + (size_t)(t0 + row) * KVDIM + g * 8, sK + pos * 8);
      int vrow = pos >> 3, vg = (pos & 7) ^ (vrow & 7);
      async_cp16(VTbase + (size_t)vrow * SEQ + t0 + vg * 8, sVT + pos * 8);
    }
    __syncthreads();

    bool active = (t0 <= q0 + wv * 32 + 31);  // wave-uniform
    if (active) {
      f32x4 Sacc[2][4] = {};
      #pragma unroll
      for (int ks = 0; ks < 4; ks++) {
        bf16x8 kf[4];
        #pragma unroll
        for (int nt = 0; nt < 4; nt++)
          kf[nt] = ld_frag(sK + (nt * 16 + l16) * 128 + (((ks * 4 + quad) ^ (l16 & 7)) * 8));
        #pragma unroll
        for (int mt = 0; mt < 2; mt++)
          #pragma unroll
          for (int nt = 0; nt < 4; nt++)
            Sacc[mt][nt] = __builtin_amdgcn_mfma_f32_16x16x32_bf16(qf[mt][ks], kf[nt], Sacc[mt][nt], 0, 0, 0);
      }
      const bool diag = (t0 + BKV - 1) > (q0 + wv * 32);
      #pragma unroll
      for (int mt = 0; mt < 2; mt++)
        #pragma unroll
        for (int nt = 0; nt < 4; nt++)
          #pragma unroll
          for (int r = 0; r < 4; r++) {
            float sv = Sacc[mt][nt][r] * scale - MFIX;
            bool msk = false;
            if (diag) {
              int qg = q0 + wv * 32 + mt * 16 + quad * 4 + r;
              int tg = t0 + nt * 16 + l16;
              msk = tg > qg;
            }
            float pv = msk ? 0.0f : __expf(sv);
            sP[(wv * 32 + mt * 16 + quad * 4 + r) * 72 + nt * 16 + l16] = f2bf(pv);
          }
      #pragma unroll
      for (int ks = 0; ks < 2; ks++) {
        bf16x8 pf[2], vf[8];
        #pragma unroll
        for (int mt = 0; mt < 2; mt++)
          pf[mt] = ld_frag(sP + (wv * 32 + mt * 16 + l16) * 72 + ks * 32 + quad * 8);
        #pragma unroll
        for (int dt = 0; dt < 8; dt++)
          vf[dt] = ld_frag(sVT + (dt * 16 + l16) * 64 + (((ks * 4 + quad) ^ (l16 & 7)) * 8));
        #pragma unroll
        for (int mt = 0; mt < 2; mt++) {
          Lacc[mt] = __builtin_amdgcn_mfma_f32_16x16x32_bf16(pf[mt], onesf, Lacc[mt], 0, 0, 0);
          #pragma unroll
          for (int dt = 0; dt < 8; dt++)
            Oacc[mt][dt] = __builtin_amdgcn_mfma_f32_16x16x32_bf16(pf[mt], vf[dt], Oacc[mt][dt], 0, 0, 0);
        }
      }
    }
    __syncthreads();
  }

  uint16_t* Op = Opart + (size_t)slot * (128 * 128);
  #pragma unroll
  for (int mt = 0; mt < 2; mt++)
    #pragma unroll
    for (int r = 0; r < 4; r++) {
      int row = wv * 32 + mt * 16 + quad * 4 + r;
      #pragma unroll
      for (int dt = 0; dt < 8; dt++)
        Op[row * 128 + dt * 16 + l16] = f2bf(Oacc[mt][dt][r]);
      if (l16 == 0)
        ml[(size_t)slot * 128 + row] = Lacc[mt][r];
    }
}

// ---------------- combine partials -> attn output (bf16) ----------------
__global__ __launch_bounds__(256) void k_combine(
    const uint16_t* __restrict__ Opart, const float* __restrict__ ml,
    uint16_t* __restrict__ attnb)
{
  const int qt = blockIdx.x;
  const int h  = blockIdx.y;
  const int nseg = (qt >> 2) + 1;
  const int slot0 = h * NPAIR + c_base[qt];
  const int tid = threadIdx.x;
  const int row = tid >> 1;
  const int dh  = (tid & 1) * 64;

  float L = 0.0f;
  #pragma unroll
  for (int i = 0; i < 4; i++)
    if (i < nseg) L += ml[(size_t)(slot0 + i) * 128 + row];
  const float invL = 1.0f / L;

  uint16_t* dst = attnb + (size_t)(qt * 128 + row) * DIM + h * HD + dh;
  #pragma unroll
  for (int c = 0; c < 8; c++) {
    int d = dh + c * 8;
    float acc[8] = {};
    #pragma unroll
    for (int i = 0; i < 4; i++) {
      if (i < nseg) {
        bf16x8 v = ld_frag(Opart + (size_t)(slot0 + i) * (128 * 128) + row * 128 + d);
        #pragma unroll
        for (int j = 0; j < 8; j++) acc[j] += (float)v[j];
      }
    }
    uint16_t outv[8];
    #pragma unroll
    for (int j = 0; j < 8; j++) outv[j] = f2bf(acc[j] * invL);
    *(uint4*)(dst + c * 8) = *(const uint4*)outv;
  }
}

// ---------------- launch ----------------
extern "C" void kernel_launch(void* const* d_in, const int* in_sizes, int n_in,
                              void* d_out, int out_size, void* d_ws, size_t ws_size,
                              hipStream_t stream) {
  const float* x  = (const float*)d_in[0];
  const float* wq = (const float*)d_in[1];
  const float* wk = (const float*)d_in[2];
  const float* wv = (const float*)d_in[3];
  const float* wo = (const float*)d_in[4];
  float* out = (float*)d_out;

  uint8_t* ws = (uint8_t*)d_ws;
  uint16_t* xb     = (uint16_t*)(ws + 0);
  uint16_t* wqkvb  = (uint16_t*)(ws + 16777216ull);
  uint16_t* Qb     = (uint16_t*)(ws + 67108864ull);
  uint16_t* Kb     = (uint16_t*)(ws + 83886080ull);
  uint16_t* Vb     = (uint16_t*)(ws + 88080384ull);
  uint16_t* VT     = (uint16_t*)(ws + 16777216ull);
  uint16_t* Opart  = (uint16_t*)(ws + 20971520ull);
  float*    mlbuf  = (float*)   (ws + 62914560ull);
  uint16_t* wob    = (uint16_t*)(ws + 16777216ull);
  uint16_t* attnb  = xb;

  k_conv_all<<<32768, 256, 0, stream>>>(x, wq, wk, wv, xb, wqkvb);
  k_gemm_qkv<<<dim3(24, 8), 512, 0, stream>>>(xb, wqkvb, Qb, Kb, Vb);
  k_vtrans<<<dim3(32, 16), 256, 0, stream>>>(Vb, VT);
  k_flash_split<<<dim3(NPAIR, 32), 256, 0, stream>>>(Qb, Kb, VT, Opart, mlbuf);
  k_combine<<<dim3(16, 32), 256, 0, stream>>>(Opart, mlbuf, attnb);
  k_conv<<<16384, 256, 0, stream>>>(wo, wob, 4194304);
  k_gemm_o<<<dim3(16, 16), 512, 0, stream>>>(attnb, wob, out);
}